// Round 5
// baseline (2193.307 us; speedup 1.0000x reference)
//
#include <hip/hip_runtime.h>

// MatchLSTM forward (Round 20): phase-B register-budget + MLP-depth fix.
//   R19 post-mortem: 1464 us, MfmaUtil 7.7 — structure right, still
//   latency-bound: only 2-3 loads in flight/wave at the 64-VGPR cap.
//   Key fact: grid=128 blocks on 256 CUs -> always 1 block/CU (16 waves =
//   4 waves/SIMD) -> HW allows 128 VGPR/wave. __launch_bounds__(1024)'s
//   default pinned 64 for an occupancy that never materializes.
//   R20: (a) __launch_bounds__(1024,4) unlocks 128 VGPRs (zero occ cost);
//        (b) GEMV1 unroll 4 (8 loads in flight), indexed addressing;
//        (c) GEMV2 single pass, 6 chains, unroll 2 (12 loads in flight).
//   Tripwire: WRITE_SIZE must stay ~5KB (spill detector).
// Phase A: Round-15 verbatim (validated).

#define DEV static __device__ __forceinline__

DEV float fast_sigmoid(float x) { return 1.0f / (1.0f + __expf(-x)); }
DEV float fast_tanh(float x)    { return 1.0f - 2.0f / (__expf(2.0f * x) + 1.0f); }

DEV unsigned f2bf(float x) {
    unsigned v = __float_as_uint(x);
    return (v + 0x7FFFu + ((v >> 16) & 1u)) >> 16;
}
DEV float blo(unsigned u) { return __uint_as_float(u << 16); }

DEV float ntload(const float* p) { return __builtin_nontemporal_load(p); }

typedef __attribute__((ext_vector_type(8))) short bfrag;   // 8 bf16
typedef __attribute__((ext_vector_type(4))) float ffrag;   // 4 fp32 acc

DEV void cvt_hilo(const float* v, bfrag& hi, bfrag& lo)
{
#pragma unroll
    for (int z = 0; z < 8; ++z) {
        unsigned h = f2bf(v[z]);
        hi[z] = (short)h;
        lo[z] = (short)f2bf(v[z] - __uint_as_float(h << 16));
    }
}

// ---------------------------------------------------------------------------
// MFMA GEMM (validated R14): C[M][512] = A[M][512] . W[512][512]^T, bf16x3.
// ---------------------------------------------------------------------------
__global__ __launch_bounds__(256) void mfma_nt_kernel(
    const float* __restrict__ A, const float* __restrict__ W,
    float* __restrict__ C)
{
    const int wv   = threadIdx.x >> 6;
    const int lane = threadIdx.x & 63;
    const int row  = lane & 15;
    const int quad = lane >> 4;
    const int m0 = blockIdx.x * 64 + wv * 16;
    const int n0 = blockIdx.y * 64;

    ffrag acc[4];
#pragma unroll
    for (int n = 0; n < 4; ++n)
#pragma unroll
        for (int r = 0; r < 4; ++r) acc[n][r] = 0.0f;

    for (int k0 = 0; k0 < 512; k0 += 32) {
        const float* ap = A + (size_t)(m0 + row) * 512 + k0 + quad * 8;
        float4 aA = *(const float4*)ap;
        float4 aB = *(const float4*)(ap + 4);
        float av[8] = {aA.x, aA.y, aA.z, aA.w, aB.x, aB.y, aB.z, aB.w};
        bfrag ahi, alo;
        cvt_hilo(av, ahi, alo);
#pragma unroll
        for (int n = 0; n < 4; ++n) {
            const float* wp = W + (size_t)(n0 + n * 16 + row) * 512 + k0 + quad * 8;
            float4 wA = *(const float4*)wp;
            float4 wB = *(const float4*)(wp + 4);
            float wvv[8] = {wA.x, wA.y, wA.z, wA.w, wB.x, wB.y, wB.z, wB.w};
            bfrag whi, wlo;
            cvt_hilo(wvv, whi, wlo);
            acc[n] = __builtin_amdgcn_mfma_f32_16x16x32_bf16(ahi, whi, acc[n], 0, 0, 0);
            acc[n] = __builtin_amdgcn_mfma_f32_16x16x32_bf16(alo, whi, acc[n], 0, 0, 0);
            acc[n] = __builtin_amdgcn_mfma_f32_16x16x32_bf16(ahi, wlo, acc[n], 0, 0, 0);
        }
    }
#pragma unroll
    for (int n = 0; n < 4; ++n)
#pragma unroll
        for (int r = 0; r < 4; ++r)
            C[(size_t)(m0 + quad * 4 + r) * 512 + n0 + n * 16 + row] = acc[n][r];
}

// ---------------------------------------------------------------------------
// 3-gate MFMA GEMM (validated R15).
// ---------------------------------------------------------------------------
template<int GATHER>
__global__ __launch_bounds__(256) void mfma_g3_kernel(
    const float* __restrict__ A, const int* __restrict__ gidx,
    int lda, int K,
    const float* __restrict__ W, int ldw,
    const float* __restrict__ bias1, const float* __restrict__ bias2,
    float* __restrict__ out)
{
    const int wv   = threadIdx.x >> 6;
    const int lane = threadIdx.x & 63;
    const int row  = lane & 15;
    const int quad = lane >> 4;
    const int m0   = blockIdx.x * 64 + wv * 16;
    const int gate = blockIdx.y >> 3;
    const int gbase = (gate == 0) ? 0 : (gate == 1 ? 1024 : 1536);
    const int j0   = (blockIdx.y & 7) * 64;

    const int arow = GATHER ? gidx[m0 + row] : (m0 + row);

    ffrag acc[4];
#pragma unroll
    for (int n = 0; n < 4; ++n)
#pragma unroll
        for (int r = 0; r < 4; ++r) acc[n][r] = 0.0f;

    for (int k0 = 0; k0 < K; k0 += 32) {
        const bool tail = (k0 + 32 > K);
        float av[8];
        if (!tail) {
            const float* ap = A + (size_t)arow * lda + k0 + quad * 8;
            float4 aA = *(const float4*)ap;
            float4 aB = *(const float4*)(ap + 4);
            av[0]=aA.x; av[1]=aA.y; av[2]=aA.z; av[3]=aA.w;
            av[4]=aB.x; av[5]=aB.y; av[6]=aB.z; av[7]=aB.w;
        } else {
#pragma unroll
            for (int z = 0; z < 8; ++z) {
                int kk = k0 + quad * 8 + z;
                av[z] = (kk < K) ? A[(size_t)arow * lda + kk] : 0.0f;
            }
        }
        bfrag ahi, alo;
        cvt_hilo(av, ahi, alo);
#pragma unroll
        for (int n = 0; n < 4; ++n) {
            const int wrow = gbase + j0 + n * 16 + row;
            float wvv[8];
            if (!tail) {
                const float* wp = W + (size_t)wrow * ldw + k0 + quad * 8;
                float4 wA = *(const float4*)wp;
                float4 wB = *(const float4*)(wp + 4);
                wvv[0]=wA.x; wvv[1]=wA.y; wvv[2]=wA.z; wvv[3]=wA.w;
                wvv[4]=wB.x; wvv[5]=wB.y; wvv[6]=wB.z; wvv[7]=wB.w;
            } else {
#pragma unroll
                for (int z = 0; z < 8; ++z) {
                    int kk = k0 + quad * 8 + z;
                    wvv[z] = (kk < K) ? W[(size_t)wrow * ldw + kk] : 0.0f;
                }
            }
            bfrag whi, wlo;
            cvt_hilo(wvv, whi, wlo);
            acc[n] = __builtin_amdgcn_mfma_f32_16x16x32_bf16(ahi, whi, acc[n], 0, 0, 0);
            acc[n] = __builtin_amdgcn_mfma_f32_16x16x32_bf16(alo, whi, acc[n], 0, 0, 0);
            acc[n] = __builtin_amdgcn_mfma_f32_16x16x32_bf16(ahi, wlo, acc[n], 0, 0, 0);
        }
    }
#pragma unroll
    for (int n = 0; n < 4; ++n) {
        const int j = j0 + n * 16 + row;
        const float bb = bias1[gbase + j] + bias2[gbase + j];
#pragma unroll
        for (int r = 0; r < 4; ++r) {
            const int m = m0 + quad * 4 + r;
            out[((size_t)m * 3 + gate) * 512 + j] = acc[n][r] + bb;
        }
    }
}

// ---------------------------------------------------------------------------
// Encoder gate math (validated R15).
// ---------------------------------------------------------------------------
__global__ __launch_bounds__(256) void enc_gates_kernel(
    const float* __restrict__ P, float* __restrict__ h)
{
    const int i = blockIdx.x * 256 + threadIdx.x;
    const int m = i >> 7;
    const int j4 = (i & 127) * 4;
    const float* p = P + (size_t)m * 1536 + j4;
    float4 gi = *(const float4*)p;
    float4 gg = *(const float4*)(p + 512);
    float4 go = *(const float4*)(p + 1024);
    float4 r;
    r.x = fast_sigmoid(go.x) * fast_tanh(fast_sigmoid(gi.x) * fast_tanh(gg.x));
    r.y = fast_sigmoid(go.y) * fast_tanh(fast_sigmoid(gi.y) * fast_tanh(gg.y));
    r.z = fast_sigmoid(go.z) * fast_tanh(fast_sigmoid(gi.z) * fast_tanh(gg.z));
    r.w = fast_sigmoid(go.w) * fast_tanh(fast_sigmoid(gi.w) * fast_tanh(gg.w));
    *(float4*)&h[(size_t)m * 512 + j4] = r;
}

// ---------------------------------------------------------------------------
// Weight pack, tile-interleaved layout for phase-B (validated R19).
//   uint4 index q = (kc*NT + nt)*64 + lane  holds the B-frag of
//   (row = nt*16 + (lane&15), k = kc*32 + (lane>>4)*8 .. +8) as 8 bf16.
// ---------------------------------------------------------------------------
__global__ __launch_bounds__(256) void pack_bf16_kernel(
    const float* __restrict__ Wm, const float* __restrict__ W3,
    unsigned* __restrict__ WmB, unsigned* __restrict__ W3B)
{
    int i = blockIdx.x * 256 + threadIdx.x;           // 0 .. 524287
    if (i < 131072) {                                  // Wm: 16*32*64*4
        int u = i & 3, lane = (i >> 2) & 63;
        int nt = (i >> 8) & 31, kc = i >> 13;
        int row = nt * 16 + (lane & 15);
        int k = kc * 32 + ((lane >> 4) << 3) + u * 2;
        unsigned lo = f2bf(Wm[(size_t)row * 512 + k]);
        unsigned hi = f2bf(Wm[(size_t)row * 512 + k + 1]);
        WmB[i] = lo | (hi << 16);
    } else {                                           // W3: 16*96*64*4
        int j = i - 131072;
        int u = j & 3, lane = (j >> 2) & 63;
        int blk = j >> 8;                              // kc*96 + nt
        int kc = blk / 96, nt = blk - kc * 96;
        int row = nt * 16 + (lane & 15);               // 0..1535
        int gate = row >> 9;
        int src  = (gate == 0 ? 0 : (gate == 1 ? 1024 : 1536)) + (row & 511);
        int k = kc * 32 + ((lane >> 4) << 3) + u * 2;
        unsigned lo = f2bf(W3[(size_t)src * 1024 + k]);
        unsigned hi = f2bf(W3[(size_t)src * 1024 + k + 1]);
        W3B[j] = lo | (hi << 16);
    }
}

// ---------------------------------------------------------------------------
// Phase B (Round 20): MFMA GEMVs, deep-MLP form at 128 VGPRs.
//   launch_bounds(1024,4): 1 block/CU (what the 128-block grid gives anyway)
//   -> 128 VGPR budget. GEMV1: 2 chains x unroll 4. GEMV2: 6 chains x
//   unroll 2 (single pass). hi/lo in A-ROWS, sum via shfl_xor 32 (R19,
//   validated).
// ---------------------------------------------------------------------------
__global__ __launch_bounds__(1024, 4) void phaseB_kernel(
    const float* __restrict__ pre_s, const float* __restrict__ pre_t,
    const float* __restrict__ h_s,   const float* __restrict__ pre_m_h,
    const unsigned* __restrict__ WmB, const unsigned* __restrict__ W3B,
    const float* __restrict__ w_e,
    const float* __restrict__ fc_w,  const float* __restrict__ fc_b,
    float* __restrict__ out)
{
    __shared__ __align__(16) float hm[512];
    __shared__ __align__(16) float base[512];
    __shared__ __align__(16) float wesh[512];
    __shared__ __align__(16) float sc[64];
    __shared__ __align__(16) float red[2 * 512];
    __shared__ __align__(16) float gates3[1536];
    __shared__ __align__(16) unsigned short hmh[512];
    __shared__ __align__(16) unsigned short hml[512];
    __shared__ __align__(16) unsigned short avh[512];
    __shared__ __align__(16) unsigned short avl[512];

    const int b    = blockIdx.x;
    const int tid  = threadIdx.x;
    const int wv   = tid >> 6;
    const int lane = tid & 63;
    const int j    = tid & 511;
    const int kh   = tid >> 9;
    const int quad = lane >> 4;

    if (tid < 512) {
        wesh[tid] = w_e[tid];
        hm[tid] = 0.0f; hmh[tid] = 0; hml[tid] = 0;
    }
    __syncthreads();

    for (int k = 0; k < 64; ++k) {
        // ---- GEMV1: base = pre_t[k,b,:] + Wm . hm
        {
            ffrag acc0 = {0.0f, 0.0f, 0.0f, 0.0f};
            ffrag acc1 = {0.0f, 0.0f, 0.0f, 0.0f};
            const uint4* wp = (const uint4*)WmB + (size_t)(wv * 2) * 64 + lane;
            const unsigned short* ab = ((lane & 8) == 0) ? hmh : hml;
#pragma unroll 4
            for (int kc = 0; kc < 16; ++kc) {
                bfrag a  = *(const bfrag*)&ab[kc * 32 + quad * 8];
                bfrag w0 = *(const bfrag*)(wp + (size_t)kc * 2048);
                bfrag w1 = *(const bfrag*)(wp + (size_t)kc * 2048 + 64);
                acc0 = __builtin_amdgcn_mfma_f32_16x16x32_bf16(a, w0, acc0, 0, 0, 0);
                acc1 = __builtin_amdgcn_mfma_f32_16x16x32_bf16(a, w1, acc1, 0, 0, 0);
            }
            float s0 = acc0[0] + __shfl_xor(acc0[0], 32);
            float s1 = acc1[0] + __shfl_xor(acc1[0], 32);
            if (lane < 32) {
                int c = lane & 15, t = lane >> 4;
                int nt = wv * 2 + t;
                float v = t ? s1 : s0;
                base[nt * 16 + c] = v
                    + ntload(&pre_t[((size_t)k * 128 + b) * 512 + nt * 16 + c]);
            }
        }
        __syncthreads();

        // ---- attention scores: e[t] = w_e . tanh(pre_s[t] + base)
#pragma unroll
        for (int tt = 0; tt < 4; ++tt) {
            int t = wv * 4 + tt;
            const float* ps = pre_s + ((size_t)t * 128 + b) * 512;
            float p = 0.0f;
#pragma unroll
            for (int u = 0; u < 8; ++u) {
                int h = lane + 64 * u;
                p += wesh[h] * fast_tanh(ntload(&ps[h]) + base[h]);
            }
#pragma unroll
            for (int off = 32; off; off >>= 1) p += __shfl_xor(p, off);
            if (lane == 0) sc[t] = p;
        }
        __syncthreads();

        // ---- softmax over 64 premise positions
        if (wv == 0) {
            float s = sc[lane], mx = s;
#pragma unroll
            for (int off = 32; off; off >>= 1) mx = fmaxf(mx, __shfl_xor(mx, off));
            float e = __expf(s - mx), sum = e;
#pragma unroll
            for (int off = 32; off; off >>= 1) sum += __shfl_xor(sum, off);
            sc[lane] = e / sum;
        }
        __syncthreads();

        // ---- a_k = sum_t alpha[t] * h_s[t,b,:]   (kh-split + LDS reduce)
        {
            const float* hp = h_s + (size_t)b * 512 + j;
            float p = 0.0f;
#pragma unroll
            for (int t4 = 0; t4 < 8; ++t4) {
                int t = kh * 32 + t4 * 4;
                float4 s4 = *(const float4*)&sc[t];
                p += s4.x * ntload(&hp[(size_t)(t + 0) * 65536])
                   + s4.y * ntload(&hp[(size_t)(t + 1) * 65536])
                   + s4.z * ntload(&hp[(size_t)(t + 2) * 65536])
                   + s4.w * ntload(&hp[(size_t)(t + 3) * 65536]);
            }
            red[kh * 512 + j] = p;
        }
        __syncthreads();
        if (tid < 512) {
            float a = red[tid] + red[512 + tid];
            unsigned h = f2bf(a);
            avh[tid] = (unsigned short)h;
            avl[tid] = (unsigned short)f2bf(a - blo(h));
        }
        __syncthreads();

        // ---- GEMV2: gates3[1536] = W3 . a_k   (single pass, 6 chains)
        {
            ffrag ac0 = {0.0f, 0.0f, 0.0f, 0.0f};
            ffrag ac1 = {0.0f, 0.0f, 0.0f, 0.0f};
            ffrag ac2 = {0.0f, 0.0f, 0.0f, 0.0f};
            ffrag ac3 = {0.0f, 0.0f, 0.0f, 0.0f};
            ffrag ac4 = {0.0f, 0.0f, 0.0f, 0.0f};
            ffrag ac5 = {0.0f, 0.0f, 0.0f, 0.0f};
            const uint4* wp = (const uint4*)W3B + (size_t)(wv * 6) * 64 + lane;
            const unsigned short* ab = ((lane & 8) == 0) ? avh : avl;
#pragma unroll 2
            for (int kc = 0; kc < 16; ++kc) {
                bfrag a  = *(const bfrag*)&ab[kc * 32 + quad * 8];
                const uint4* wk = wp + (size_t)kc * 6144;
                bfrag w0 = *(const bfrag*)(wk);
                bfrag w1 = *(const bfrag*)(wk + 64);
                bfrag w2 = *(const bfrag*)(wk + 128);
                bfrag w3 = *(const bfrag*)(wk + 192);
                bfrag w4 = *(const bfrag*)(wk + 256);
                bfrag w5 = *(const bfrag*)(wk + 320);
                ac0 = __builtin_amdgcn_mfma_f32_16x16x32_bf16(a, w0, ac0, 0, 0, 0);
                ac1 = __builtin_amdgcn_mfma_f32_16x16x32_bf16(a, w1, ac1, 0, 0, 0);
                ac2 = __builtin_amdgcn_mfma_f32_16x16x32_bf16(a, w2, ac2, 0, 0, 0);
                ac3 = __builtin_amdgcn_mfma_f32_16x16x32_bf16(a, w3, ac3, 0, 0, 0);
                ac4 = __builtin_amdgcn_mfma_f32_16x16x32_bf16(a, w4, ac4, 0, 0, 0);
                ac5 = __builtin_amdgcn_mfma_f32_16x16x32_bf16(a, w5, ac5, 0, 0, 0);
            }
            float s0 = ac0[0] + __shfl_xor(ac0[0], 32);
            float s1 = ac1[0] + __shfl_xor(ac1[0], 32);
            float s2 = ac2[0] + __shfl_xor(ac2[0], 32);
            float s3 = ac3[0] + __shfl_xor(ac3[0], 32);
            float s4 = ac4[0] + __shfl_xor(ac4[0], 32);
            float s5 = ac5[0] + __shfl_xor(ac5[0], 32);
            if (lane < 16) {
                gates3[(wv * 6 + 0) * 16 + lane] = s0;
                gates3[(wv * 6 + 1) * 16 + lane] = s1;
                gates3[(wv * 6 + 2) * 16 + lane] = s2;
                gates3[(wv * 6 + 3) * 16 + lane] = s3;
                gates3[(wv * 6 + 4) * 16 + lane] = s4;
                gates3[(wv * 6 + 5) * 16 + lane] = s5;
            }
        }
        __syncthreads();

        // ---- gate math -> hm (+ hi/lo pack for next step's GEMV1)
        if (tid < 512) {
            const size_t m = (size_t)k * 128 + b;
            float gi = gates3[tid]        + ntload(&pre_m_h[(m * 3 + 0) * 512 + tid]);
            float gg = gates3[512 + tid]  + ntload(&pre_m_h[(m * 3 + 1) * 512 + tid]);
            float go = gates3[1024 + tid] + ntload(&pre_m_h[(m * 3 + 2) * 512 + tid]);
            float cc = fast_sigmoid(gi) * fast_tanh(gg);
            float hv = fast_sigmoid(go) * fast_tanh(cc);
            hm[tid] = hv;
            unsigned hb = f2bf(hv);
            hmh[tid] = (unsigned short)hb;
            hml[tid] = (unsigned short)f2bf(hv - blo(hb));
        }
        __syncthreads();
    }

    if (wv < 3) {
        float p = 0.0f;
#pragma unroll
        for (int u = 0; u < 8; ++u) {
            int h = lane + 64 * u;
            p += hm[h] * fc_w[wv * 512 + h];
        }
#pragma unroll
        for (int off = 32; off; off >>= 1) p += __shfl_xor(p, off);
        if (lane == 0) out[b * 3 + wv] = p + fc_b[wv];
    }
}

extern "C" void kernel_launch(void* const* d_in, const int* in_sizes, int n_in,
                              void* d_out, int out_size, void* d_ws, size_t ws_size,
                              hipStream_t stream)
{
    (void)in_sizes; (void)n_in; (void)out_size;
    const int*   premise    = (const int*)d_in[0];
    const int*   hypothesis = (const int*)d_in[2];
    const float* embed  = (const float*)d_in[4];
    const float* w_e    = (const float*)d_in[5];
    const float* Ws     = (const float*)d_in[6];
    const float* Wt     = (const float*)d_in[7];
    const float* Wm     = (const float*)d_in[8];
    const float* Wih_p  = (const float*)d_in[9];
    const float* bih_p  = (const float*)d_in[10];
    const float* bhh_p  = (const float*)d_in[11];
    const float* Wih_h  = (const float*)d_in[12];
    const float* bih_h  = (const float*)d_in[13];
    const float* bhh_h  = (const float*)d_in[14];
    const float* Wih_m  = (const float*)d_in[15];
    const float* bih_m  = (const float*)d_in[16];
    const float* bhh_m  = (const float*)d_in[17];
    const float* fc_w   = (const float*)d_in[18];
    const float* fc_b   = (const float*)d_in[19];

    float* ws      = (float*)d_ws;
    float* h_s     = ws;                      // 8192*512
    float* h_t     = h_s    + 4194304;        // 8192*512 (aliased by packs)
    float* pre_s   = h_t    + 4194304;
    float* pre_t   = pre_s  + 4194304;
    float* pre_m_h = pre_t  + 4194304;        // 8192*3*512 (+ encoder scratch)
    unsigned* WmB  = (unsigned*)h_t;          // aliases h_t after last reader
    unsigned* W3B  = WmB + 131072;            // 512KB + 1.5MB << 16MB region
    float* outp    = (float*)d_out;
    if (ws_size < (size_t)29556736 * 4) return;

    dim3 blk(256);
    float* P = pre_m_h;                       // encoder preact scratch

    // Phase A (all MFMA, validated)
    mfma_g3_kernel<1><<<dim3(128, 24), blk, 0, stream>>>(
        embed, premise, 300, 300, Wih_p, 300, bih_p, bhh_p, P);
    enc_gates_kernel<<<4096, blk, 0, stream>>>(P, h_s);
    mfma_g3_kernel<1><<<dim3(128, 24), blk, 0, stream>>>(
        embed, hypothesis, 300, 300, Wih_h, 300, bih_h, bhh_h, P);
    enc_gates_kernel<<<4096, blk, 0, stream>>>(P, h_t);
    mfma_nt_kernel<<<dim3(128, 8), blk, 0, stream>>>(h_s, Ws, pre_s);
    mfma_nt_kernel<<<dim3(128, 8), blk, 0, stream>>>(h_t, Wt, pre_t);
    mfma_g3_kernel<0><<<dim3(128, 24), blk, 0, stream>>>(
        h_t, nullptr, 512, 512, Wih_m + 512, 1024, bih_m, bhh_m, pre_m_h);

    // Weight pack (after h_t's last reader; output aliases h_t space)
    pack_bf16_kernel<<<2048, blk, 0, stream>>>(Wm, Wih_m, WmB, W3B);

    // Phase B (MFMA GEMVs, 128-VGPR deep-MLP)
    phaseB_kernel<<<dim3(128), dim3(1024), 0, stream>>>(
        pre_s, pre_t, h_s, pre_m_h, WmB, W3B, w_e, fc_w, fc_b, outp);
}

// Round 6
// 2035.558 us; speedup vs baseline: 1.0775x; 1.0775x over previous
//
#include <hip/hip_runtime.h>

// MatchLSTM forward (Round 21): algebraic restructuring of phase B.
//   R19/R20 counters pinned the floor: each CU streams 2MB weights/step
//   through a ~64B/cy L2 port -> >=13.6us/step. Fix: gates3 = W3.a_k =
//   sum_t alpha_t (W3.h_s[t]) -- precompute G3[t,b,:] = W3.h_s[t,b] ONCE
//   (phase A MFMA GEMM, bf16), then phase B reads 196KB/step of G3 instead
//   of 1.5MB/step of W3. a_k never materialized; h_s not read in phase B.
//   GEMV1 (Wm.hm, 512KB/step) stays R19-verbatim. VGPR cap 64 respected.
//   Workspace: h_s/h_t computed in 4096-row halves; encoder preact scratch
//   aliased inside pre_m_h; total 29,360,128 floats < old guard.
// Phase A kernels: R15-validated cores; g3pack = mfma_g3 core + bf16
//   pair-packed epilogue (layout [tpair][b][gate][j][2]).

#define DEV static __device__ __forceinline__

DEV float fast_sigmoid(float x) { return 1.0f / (1.0f + __expf(-x)); }
DEV float fast_tanh(float x)    { return 1.0f - 2.0f / (__expf(2.0f * x) + 1.0f); }

DEV unsigned f2bf(float x) {
    unsigned v = __float_as_uint(x);
    return (v + 0x7FFFu + ((v >> 16) & 1u)) >> 16;
}
DEV float blo(unsigned u) { return __uint_as_float(u << 16); }
DEV float bhi(unsigned u) { return __uint_as_float(u & 0xFFFF0000u); }

DEV float ntload(const float* p) { return __builtin_nontemporal_load(p); }

typedef __attribute__((ext_vector_type(8))) short bfrag;   // 8 bf16
typedef __attribute__((ext_vector_type(4))) float ffrag;   // 4 fp32 acc

DEV void cvt_hilo(const float* v, bfrag& hi, bfrag& lo)
{
#pragma unroll
    for (int z = 0; z < 8; ++z) {
        unsigned h = f2bf(v[z]);
        hi[z] = (short)h;
        lo[z] = (short)f2bf(v[z] - __uint_as_float(h << 16));
    }
}

// ---------------------------------------------------------------------------
// MFMA GEMM (validated R14): C[M][512] = A[M][512] . W[512][512]^T, bf16x3.
// ---------------------------------------------------------------------------
__global__ __launch_bounds__(256) void mfma_nt_kernel(
    const float* __restrict__ A, const float* __restrict__ W,
    float* __restrict__ C)
{
    const int wv   = threadIdx.x >> 6;
    const int lane = threadIdx.x & 63;
    const int row  = lane & 15;
    const int quad = lane >> 4;
    const int m0 = blockIdx.x * 64 + wv * 16;
    const int n0 = blockIdx.y * 64;

    ffrag acc[4];
#pragma unroll
    for (int n = 0; n < 4; ++n)
#pragma unroll
        for (int r = 0; r < 4; ++r) acc[n][r] = 0.0f;

    for (int k0 = 0; k0 < 512; k0 += 32) {
        const float* ap = A + (size_t)(m0 + row) * 512 + k0 + quad * 8;
        float4 aA = *(const float4*)ap;
        float4 aB = *(const float4*)(ap + 4);
        float av[8] = {aA.x, aA.y, aA.z, aA.w, aB.x, aB.y, aB.z, aB.w};
        bfrag ahi, alo;
        cvt_hilo(av, ahi, alo);
#pragma unroll
        for (int n = 0; n < 4; ++n) {
            const float* wp = W + (size_t)(n0 + n * 16 + row) * 512 + k0 + quad * 8;
            float4 wA = *(const float4*)wp;
            float4 wB = *(const float4*)(wp + 4);
            float wvv[8] = {wA.x, wA.y, wA.z, wA.w, wB.x, wB.y, wB.z, wB.w};
            bfrag whi, wlo;
            cvt_hilo(wvv, whi, wlo);
            acc[n] = __builtin_amdgcn_mfma_f32_16x16x32_bf16(ahi, whi, acc[n], 0, 0, 0);
            acc[n] = __builtin_amdgcn_mfma_f32_16x16x32_bf16(alo, whi, acc[n], 0, 0, 0);
            acc[n] = __builtin_amdgcn_mfma_f32_16x16x32_bf16(ahi, wlo, acc[n], 0, 0, 0);
        }
    }
#pragma unroll
    for (int n = 0; n < 4; ++n)
#pragma unroll
        for (int r = 0; r < 4; ++r)
            C[(size_t)(m0 + quad * 4 + r) * 512 + n0 + n * 16 + row] = acc[n][r];
}

// ---------------------------------------------------------------------------
// 3-gate MFMA GEMM (validated R15): fp32 out + biases.
// ---------------------------------------------------------------------------
template<int GATHER>
__global__ __launch_bounds__(256) void mfma_g3_kernel(
    const float* __restrict__ A, const int* __restrict__ gidx,
    int lda, int K,
    const float* __restrict__ W, int ldw,
    const float* __restrict__ bias1, const float* __restrict__ bias2,
    float* __restrict__ out)
{
    const int wv   = threadIdx.x >> 6;
    const int lane = threadIdx.x & 63;
    const int row  = lane & 15;
    const int quad = lane >> 4;
    const int m0   = blockIdx.x * 64 + wv * 16;
    const int gate = blockIdx.y >> 3;
    const int gbase = (gate == 0) ? 0 : (gate == 1 ? 1024 : 1536);
    const int j0   = (blockIdx.y & 7) * 64;

    const int arow = GATHER ? gidx[m0 + row] : (m0 + row);

    ffrag acc[4];
#pragma unroll
    for (int n = 0; n < 4; ++n)
#pragma unroll
        for (int r = 0; r < 4; ++r) acc[n][r] = 0.0f;

    for (int k0 = 0; k0 < K; k0 += 32) {
        const bool tail = (k0 + 32 > K);
        float av[8];
        if (!tail) {
            const float* ap = A + (size_t)arow * lda + k0 + quad * 8;
            float4 aA = *(const float4*)ap;
            float4 aB = *(const float4*)(ap + 4);
            av[0]=aA.x; av[1]=aA.y; av[2]=aA.z; av[3]=aA.w;
            av[4]=aB.x; av[5]=aB.y; av[6]=aB.z; av[7]=aB.w;
        } else {
#pragma unroll
            for (int z = 0; z < 8; ++z) {
                int kk = k0 + quad * 8 + z;
                av[z] = (kk < K) ? A[(size_t)arow * lda + kk] : 0.0f;
            }
        }
        bfrag ahi, alo;
        cvt_hilo(av, ahi, alo);
#pragma unroll
        for (int n = 0; n < 4; ++n) {
            const int wrow = gbase + j0 + n * 16 + row;
            float wvv[8];
            if (!tail) {
                const float* wp = W + (size_t)wrow * ldw + k0 + quad * 8;
                float4 wA = *(const float4*)wp;
                float4 wB = *(const float4*)(wp + 4);
                wvv[0]=wA.x; wvv[1]=wA.y; wvv[2]=wA.z; wvv[3]=wA.w;
                wvv[4]=wB.x; wvv[5]=wB.y; wvv[6]=wB.z; wvv[7]=wB.w;
            } else {
#pragma unroll
                for (int z = 0; z < 8; ++z) {
                    int kk = k0 + quad * 8 + z;
                    wvv[z] = (kk < K) ? W[(size_t)wrow * ldw + kk] : 0.0f;
                }
            }
            bfrag whi, wlo;
            cvt_hilo(wvv, whi, wlo);
            acc[n] = __builtin_amdgcn_mfma_f32_16x16x32_bf16(ahi, whi, acc[n], 0, 0, 0);
            acc[n] = __builtin_amdgcn_mfma_f32_16x16x32_bf16(alo, whi, acc[n], 0, 0, 0);
            acc[n] = __builtin_amdgcn_mfma_f32_16x16x32_bf16(ahi, wlo, acc[n], 0, 0, 0);
        }
    }
#pragma unroll
    for (int n = 0; n < 4; ++n) {
        const int j = j0 + n * 16 + row;
        const float bb = bias1[gbase + j] + bias2[gbase + j];
#pragma unroll
        for (int r = 0; r < 4; ++r) {
            const int m = m0 + quad * 4 + r;
            out[((size_t)m * 3 + gate) * 512 + j] = acc[n][r] + bb;
        }
    }
}

// ---------------------------------------------------------------------------
// NEW (R21): G3 GEMM. G3[t,b,:] = W3 . h_s[t,b,:]  (a_k-part of Wih_m,
// rows {i:0-511, g:1024-1535, o:1536-2047}, cols 0:512; NO biases).
// Output bf16, pair-packed over t: ushort index
//   (((t>>1)*128 + b)*1536 + gate*512 + j)*2 + (t&1)
// so phase B reads one uint = {t even, t odd} per (b, gate, j).
// Core = validated mfma_g3 bf16x3 loop (K=512, lda=512, ldw=1024).
// ---------------------------------------------------------------------------
__global__ __launch_bounds__(256) void g3pack_kernel(
    const float* __restrict__ A,            // Rh: 4096 x 512
    const float* __restrict__ W,            // Wih_m, ldw 1024
    unsigned short* __restrict__ G3s,
    int mbase)                              // 0 or 4096
{
    const int wv   = threadIdx.x >> 6;
    const int lane = threadIdx.x & 63;
    const int row  = lane & 15;
    const int quad = lane >> 4;
    const int m0   = blockIdx.x * 64 + wv * 16;
    const int gate = blockIdx.y >> 3;
    const int gbase = (gate == 0) ? 0 : (gate == 1 ? 1024 : 1536);
    const int j0   = (blockIdx.y & 7) * 64;

    ffrag acc[4];
#pragma unroll
    for (int n = 0; n < 4; ++n)
#pragma unroll
        for (int r = 0; r < 4; ++r) acc[n][r] = 0.0f;

    for (int k0 = 0; k0 < 512; k0 += 32) {
        const float* ap = A + (size_t)(m0 + row) * 512 + k0 + quad * 8;
        float4 aA = *(const float4*)ap;
        float4 aB = *(const float4*)(ap + 4);
        float av[8] = {aA.x, aA.y, aA.z, aA.w, aB.x, aB.y, aB.z, aB.w};
        bfrag ahi, alo;
        cvt_hilo(av, ahi, alo);
#pragma unroll
        for (int n = 0; n < 4; ++n) {
            const int wrow = gbase + j0 + n * 16 + row;
            const float* wp = W + (size_t)wrow * 1024 + k0 + quad * 8;
            float4 wA = *(const float4*)wp;
            float4 wB = *(const float4*)(wp + 4);
            float wvv[8] = {wA.x, wA.y, wA.z, wA.w, wB.x, wB.y, wB.z, wB.w};
            bfrag whi, wlo;
            cvt_hilo(wvv, whi, wlo);
            acc[n] = __builtin_amdgcn_mfma_f32_16x16x32_bf16(ahi, whi, acc[n], 0, 0, 0);
            acc[n] = __builtin_amdgcn_mfma_f32_16x16x32_bf16(alo, whi, acc[n], 0, 0, 0);
            acc[n] = __builtin_amdgcn_mfma_f32_16x16x32_bf16(ahi, wlo, acc[n], 0, 0, 0);
        }
    }
#pragma unroll
    for (int n = 0; n < 4; ++n) {
        const int j = j0 + n * 16 + row;
#pragma unroll
        for (int r = 0; r < 4; ++r) {
            const int mg = mbase + m0 + quad * 4 + r;
            const int t = mg >> 7, b = mg & 127;
            size_t idx = (((size_t)(t >> 1) * 128 + b) * 1536 + gate * 512 + j) * 2
                       + (t & 1);
            G3s[idx] = (unsigned short)f2bf(acc[n][r]);
        }
    }
}

// ---------------------------------------------------------------------------
// Encoder gate math (validated R15). Grid covers M*128 threads-worth.
// ---------------------------------------------------------------------------
__global__ __launch_bounds__(256) void enc_gates_kernel(
    const float* __restrict__ P, float* __restrict__ h)
{
    const int i = blockIdx.x * 256 + threadIdx.x;
    const int m = i >> 7;
    const int j4 = (i & 127) * 4;
    const float* p = P + (size_t)m * 1536 + j4;
    float4 gi = *(const float4*)p;
    float4 gg = *(const float4*)(p + 512);
    float4 go = *(const float4*)(p + 1024);
    float4 r;
    r.x = fast_sigmoid(go.x) * fast_tanh(fast_sigmoid(gi.x) * fast_tanh(gg.x));
    r.y = fast_sigmoid(go.y) * fast_tanh(fast_sigmoid(gi.y) * fast_tanh(gg.y));
    r.z = fast_sigmoid(go.z) * fast_tanh(fast_sigmoid(gi.z) * fast_tanh(gg.z));
    r.w = fast_sigmoid(go.w) * fast_tanh(fast_sigmoid(gi.w) * fast_tanh(gg.w));
    *(float4*)&h[(size_t)m * 512 + j4] = r;
}

// ---------------------------------------------------------------------------
// Wm pack (R19's validated WmB branch): [kc][nt][lane] tile-interleaved.
// ---------------------------------------------------------------------------
__global__ __launch_bounds__(256) void pack_wm_kernel(
    const float* __restrict__ Wm, unsigned* __restrict__ WmB)
{
    int i = blockIdx.x * 256 + threadIdx.x;           // 0 .. 131071
    int u = i & 3, lane = (i >> 2) & 63;
    int nt = (i >> 8) & 31, kc = i >> 13;
    int row = nt * 16 + (lane & 15);
    int k = kc * 32 + ((lane >> 4) << 3) + u * 2;
    unsigned lo = f2bf(Wm[(size_t)row * 512 + k]);
    unsigned hi = f2bf(Wm[(size_t)row * 512 + k + 1]);
    WmB[i] = lo | (hi << 16);
}

// ---------------------------------------------------------------------------
// Phase B (Round 21): GEMV1 (R19 verbatim) + G3 weighted-sum GEMV2.
// ---------------------------------------------------------------------------
__global__ __launch_bounds__(1024) void phaseB_kernel(
    const float* __restrict__ pre_s, const float* __restrict__ pre_t,
    const float* __restrict__ pre_m_h,
    const unsigned* __restrict__ WmB, const unsigned* __restrict__ G3u,
    const float* __restrict__ w_e,
    const float* __restrict__ fc_w,  const float* __restrict__ fc_b,
    float* __restrict__ out)
{
    __shared__ __align__(16) float hm[512];
    __shared__ __align__(16) float base[512];
    __shared__ __align__(16) float wesh[512];
    __shared__ __align__(16) float sc[64];
    __shared__ __align__(16) float red3[3 * 2 * 512];
    __shared__ __align__(16) unsigned short hmh[512];
    __shared__ __align__(16) unsigned short hml[512];

    const int b    = blockIdx.x;
    const int tid  = threadIdx.x;
    const int wv   = tid >> 6;
    const int lane = tid & 63;
    const int j    = tid & 511;
    const int kh   = tid >> 9;
    const int quad = lane >> 4;

    if (tid < 512) {
        wesh[tid] = w_e[tid];
        hm[tid] = 0.0f; hmh[tid] = 0; hml[tid] = 0;
    }
    __syncthreads();

    for (int k = 0; k < 64; ++k) {
        // ---- GEMV1: base = pre_t[k,b,:] + Wm . hm   (R19 verbatim)
        {
            ffrag acc0 = {0.0f, 0.0f, 0.0f, 0.0f};
            ffrag acc1 = {0.0f, 0.0f, 0.0f, 0.0f};
            const uint4* wp = (const uint4*)WmB + (size_t)(wv * 2) * 64 + lane;
            const unsigned short* ab = ((lane & 8) == 0) ? hmh : hml;
#pragma unroll 1
            for (int kc = 0; kc < 16; ++kc) {
                bfrag a  = *(const bfrag*)&ab[kc * 32 + quad * 8];
                bfrag w0 = *(const bfrag*)(wp);
                bfrag w1 = *(const bfrag*)(wp + 64);
                acc0 = __builtin_amdgcn_mfma_f32_16x16x32_bf16(a, w0, acc0, 0, 0, 0);
                acc1 = __builtin_amdgcn_mfma_f32_16x16x32_bf16(a, w1, acc1, 0, 0, 0);
                wp += 2048;                            // next kc (32 tiles * 64)
            }
            float s0 = acc0[0] + __shfl_xor(acc0[0], 32);
            float s1 = acc1[0] + __shfl_xor(acc1[0], 32);
            if (lane < 32) {
                int c = lane & 15, t = lane >> 4;
                int nt = wv * 2 + t;
                float v = t ? s1 : s0;
                base[nt * 16 + c] = v
                    + ntload(&pre_t[((size_t)k * 128 + b) * 512 + nt * 16 + c]);
            }
        }
        __syncthreads();

        // ---- attention scores: e[t] = w_e . tanh(pre_s[t] + base)
#pragma unroll
        for (int tt = 0; tt < 4; ++tt) {
            int t = wv * 4 + tt;
            const float* ps = pre_s + ((size_t)t * 128 + b) * 512;
            float p = 0.0f;
#pragma unroll
            for (int u = 0; u < 8; ++u) {
                int h = lane + 64 * u;
                p += wesh[h] * fast_tanh(ntload(&ps[h]) + base[h]);
            }
#pragma unroll
            for (int off = 32; off; off >>= 1) p += __shfl_xor(p, off);
            if (lane == 0) sc[t] = p;
        }
        __syncthreads();

        // ---- softmax over 64 premise positions
        if (wv == 0) {
            float s = sc[lane], mx = s;
#pragma unroll
            for (int off = 32; off; off >>= 1) mx = fmaxf(mx, __shfl_xor(mx, off));
            float e = __expf(s - mx), sum = e;
#pragma unroll
            for (int off = 32; off; off >>= 1) sum += __shfl_xor(sum, off);
            sc[lane] = e / sum;
        }
        __syncthreads();

        // ---- NEW: gates partials = sum_t alpha_t * G3[t,b,:]
        //      thread (j, kh): t-pairs tp in [kh*16, kh*16+16), 3 gates.
        {
            const unsigned* gb = G3u + ((size_t)(kh * 16) * 128 + b) * 1536 + j;
            float p0 = 0.0f, p1 = 0.0f, p2 = 0.0f;
#pragma unroll 2
            for (int tpi = 0; tpi < 16; ++tpi) {
                const unsigned* gt = gb + (size_t)tpi * 196608;   // 128*1536
                unsigned u0 = gt[0];
                unsigned u1 = gt[512];
                unsigned u2 = gt[1024];
                float2 al = *(const float2*)&sc[(kh * 16 + tpi) * 2];
                p0 += blo(u0) * al.x + bhi(u0) * al.y;
                p1 += blo(u1) * al.x + bhi(u1) * al.y;
                p2 += blo(u2) * al.x + bhi(u2) * al.y;
            }
            red3[kh * 512 + j]            = p0;
            red3[(2 + kh) * 512 + j]      = p1;
            red3[(4 + kh) * 512 + j]      = p2;
        }
        __syncthreads();

        // ---- gate math -> hm (+ hi/lo pack for next step's GEMV1)
        if (tid < 512) {
            const size_t m = (size_t)k * 128 + b;
            float gi = red3[tid]        + red3[512 + tid]
                     + ntload(&pre_m_h[(m * 3 + 0) * 512 + tid]);
            float gg = red3[1024 + tid] + red3[1536 + tid]
                     + ntload(&pre_m_h[(m * 3 + 1) * 512 + tid]);
            float go = red3[2048 + tid] + red3[2560 + tid]
                     + ntload(&pre_m_h[(m * 3 + 2) * 512 + tid]);
            float cc = fast_sigmoid(gi) * fast_tanh(gg);
            float hv = fast_sigmoid(go) * fast_tanh(cc);
            hm[tid] = hv;
            unsigned hb = f2bf(hv);
            hmh[tid] = (unsigned short)hb;
            hml[tid] = (unsigned short)f2bf(hv - blo(hb));
        }
        __syncthreads();
    }

    if (wv < 3) {
        float p = 0.0f;
#pragma unroll
        for (int u = 0; u < 8; ++u) {
            int h = lane + 64 * u;
            p += hm[h] * fc_w[wv * 512 + h];
        }
#pragma unroll
        for (int off = 32; off; off >>= 1) p += __shfl_xor(p, off);
        if (lane == 0) out[b * 3 + wv] = p + fc_b[wv];
    }
}

extern "C" void kernel_launch(void* const* d_in, const int* in_sizes, int n_in,
                              void* d_out, int out_size, void* d_ws, size_t ws_size,
                              hipStream_t stream)
{
    (void)in_sizes; (void)n_in; (void)out_size;
    const int*   premise    = (const int*)d_in[0];
    const int*   hypothesis = (const int*)d_in[2];
    const float* embed  = (const float*)d_in[4];
    const float* w_e    = (const float*)d_in[5];
    const float* Ws     = (const float*)d_in[6];
    const float* Wt     = (const float*)d_in[7];
    const float* Wm     = (const float*)d_in[8];
    const float* Wih_p  = (const float*)d_in[9];
    const float* bih_p  = (const float*)d_in[10];
    const float* bhh_p  = (const float*)d_in[11];
    const float* Wih_h  = (const float*)d_in[12];
    const float* bih_h  = (const float*)d_in[13];
    const float* bhh_h  = (const float*)d_in[14];
    const float* Wih_m  = (const float*)d_in[15];
    const float* bih_m  = (const float*)d_in[16];
    const float* bhh_m  = (const float*)d_in[17];
    const float* fc_w   = (const float*)d_in[18];
    const float* fc_b   = (const float*)d_in[19];

    // Workspace layout (floats), total 29,360,128 <= old guard 29,556,736:
    //   Rh      @ 0         : 2,097,152  (4096x512 half-scratch; WmB aliases)
    //   pre_s   @ 2,097,152 : 4,194,304
    //   pre_t   @ 6,291,456 : 4,194,304
    //   pre_m_h @10,485,760 :12,582,912  (first/second 6,291,456 also = P(h))
    //   G3      @23,068,672 : 6,291,456  (bf16 pairs as uints)
    float* ws      = (float*)d_ws;
    float* Rh      = ws;
    float* pre_s   = ws + 2097152;
    float* pre_t   = ws + 6291456;
    float* pre_m_h = ws + 10485760;
    unsigned* G3u  = (unsigned*)(ws + 23068672);
    unsigned short* G3s = (unsigned short*)G3u;
    unsigned* WmB  = (unsigned*)Rh;           // aliases Rh after last reader
    float* outp    = (float*)d_out;
    if (ws_size < (size_t)29556736 * 4) return;

    dim3 blk(256);

    // ---- Phase A: premise halves -> h_s(half) -> pre_s(half), G3(half)
    for (int h = 0; h < 2; ++h) {
        float* P = pre_m_h + (size_t)h * 6291456;   // preact scratch (safe)
        mfma_g3_kernel<1><<<dim3(64, 24), blk, 0, stream>>>(
            embed, premise + h * 4096, 300, 300, Wih_p, 300, bih_p, bhh_p, P);
        enc_gates_kernel<<<2048, blk, 0, stream>>>(P, Rh);
        mfma_nt_kernel<<<dim3(64, 8), blk, 0, stream>>>(
            Rh, Ws, pre_s + (size_t)h * 2097152);
        g3pack_kernel<<<dim3(64, 24), blk, 0, stream>>>(
            Rh, Wih_m, G3s, h * 4096);
    }
    // ---- Phase A: hypothesis halves -> h_t(half) -> pre_t(half), pre_m_h(half)
    for (int h = 0; h < 2; ++h) {
        float* P = pre_m_h + (size_t)h * 6291456;   // overwritten by output after last read
        mfma_g3_kernel<1><<<dim3(64, 24), blk, 0, stream>>>(
            embed, hypothesis + h * 4096, 300, 300, Wih_h, 300, bih_h, bhh_h, P);
        enc_gates_kernel<<<2048, blk, 0, stream>>>(P, Rh);
        mfma_nt_kernel<<<dim3(64, 8), blk, 0, stream>>>(
            Rh, Wt, pre_t + (size_t)h * 2097152);
        mfma_g3_kernel<0><<<dim3(64, 24), blk, 0, stream>>>(
            Rh, nullptr, 512, 512, Wih_m + 512, 1024, bih_m, bhh_m,
            pre_m_h + (size_t)h * 6291456);
    }

    // ---- Wm pack (after Rh's last reader; output aliases Rh)
    pack_wm_kernel<<<512, blk, 0, stream>>>(Wm, WmB);

    // ---- Phase B
    phaseB_kernel<<<dim3(128), dim3(1024), 0, stream>>>(
        pre_s, pre_t, pre_m_h, WmB, G3u, w_e, fc_w, fc_b, outp);
}

// Round 7
// 1822.867 us; speedup vs baseline: 1.2032x; 1.1167x over previous
//
#include <hip/hip_runtime.h>

// MatchLSTM forward (Round 22): kill the phase-B L2 thrash.
//   R21 counters: FETCH 311MB @ 285GB/s, MfmaUtil 2.4 -> latency-bound on
//   HBM misses. Working set/XCD/step = G3 3.1MB + pre_s 2MB + Wm 0.5MB >
//   4MB L2 -> thrash. R22:
//   (a) pre_s LDS-cached once per kernel (128KB dynamic LDS + FuncSetAttr;
//       static 20KB + dyn 128KB = 148KB <= 160KB). Scores = LDS+VALU only.
//       Frees 2MB/XCD -> G3+Wm fit L2 -> misses become ~250cy hits.
//   (b) GEMV1 K-split across wave halves: 8 serial iters, 4 tiles x 4
//       chains/wave, partials via red3 (+1 barrier).
//   (c) G3-sum unroll 4.
//   Numerics unchanged (pre_s exact fp32 in LDS; fp32 regroup only).
// Phase A: R21 verbatim (validated; absmax 9.77e-4).

#define DEV static __device__ __forceinline__

DEV float fast_sigmoid(float x) { return 1.0f / (1.0f + __expf(-x)); }
DEV float fast_tanh(float x)    { return 1.0f - 2.0f / (__expf(2.0f * x) + 1.0f); }

DEV unsigned f2bf(float x) {
    unsigned v = __float_as_uint(x);
    return (v + 0x7FFFu + ((v >> 16) & 1u)) >> 16;
}
DEV float blo(unsigned u) { return __uint_as_float(u << 16); }
DEV float bhi(unsigned u) { return __uint_as_float(u & 0xFFFF0000u); }

DEV float ntload(const float* p) { return __builtin_nontemporal_load(p); }

typedef __attribute__((ext_vector_type(8))) short bfrag;   // 8 bf16
typedef __attribute__((ext_vector_type(4))) float ffrag;   // 4 fp32 acc

DEV void cvt_hilo(const float* v, bfrag& hi, bfrag& lo)
{
#pragma unroll
    for (int z = 0; z < 8; ++z) {
        unsigned h = f2bf(v[z]);
        hi[z] = (short)h;
        lo[z] = (short)f2bf(v[z] - __uint_as_float(h << 16));
    }
}

// ---------------------------------------------------------------------------
// MFMA GEMM (validated R14): C[M][512] = A[M][512] . W[512][512]^T, bf16x3.
// ---------------------------------------------------------------------------
__global__ __launch_bounds__(256) void mfma_nt_kernel(
    const float* __restrict__ A, const float* __restrict__ W,
    float* __restrict__ C)
{
    const int wv   = threadIdx.x >> 6;
    const int lane = threadIdx.x & 63;
    const int row  = lane & 15;
    const int quad = lane >> 4;
    const int m0 = blockIdx.x * 64 + wv * 16;
    const int n0 = blockIdx.y * 64;

    ffrag acc[4];
#pragma unroll
    for (int n = 0; n < 4; ++n)
#pragma unroll
        for (int r = 0; r < 4; ++r) acc[n][r] = 0.0f;

    for (int k0 = 0; k0 < 512; k0 += 32) {
        const float* ap = A + (size_t)(m0 + row) * 512 + k0 + quad * 8;
        float4 aA = *(const float4*)ap;
        float4 aB = *(const float4*)(ap + 4);
        float av[8] = {aA.x, aA.y, aA.z, aA.w, aB.x, aB.y, aB.z, aB.w};
        bfrag ahi, alo;
        cvt_hilo(av, ahi, alo);
#pragma unroll
        for (int n = 0; n < 4; ++n) {
            const float* wp = W + (size_t)(n0 + n * 16 + row) * 512 + k0 + quad * 8;
            float4 wA = *(const float4*)wp;
            float4 wB = *(const float4*)(wp + 4);
            float wvv[8] = {wA.x, wA.y, wA.z, wA.w, wB.x, wB.y, wB.z, wB.w};
            bfrag whi, wlo;
            cvt_hilo(wvv, whi, wlo);
            acc[n] = __builtin_amdgcn_mfma_f32_16x16x32_bf16(ahi, whi, acc[n], 0, 0, 0);
            acc[n] = __builtin_amdgcn_mfma_f32_16x16x32_bf16(alo, whi, acc[n], 0, 0, 0);
            acc[n] = __builtin_amdgcn_mfma_f32_16x16x32_bf16(ahi, wlo, acc[n], 0, 0, 0);
        }
    }
#pragma unroll
    for (int n = 0; n < 4; ++n)
#pragma unroll
        for (int r = 0; r < 4; ++r)
            C[(size_t)(m0 + quad * 4 + r) * 512 + n0 + n * 16 + row] = acc[n][r];
}

// ---------------------------------------------------------------------------
// 3-gate MFMA GEMM (validated R15): fp32 out + biases.
// ---------------------------------------------------------------------------
template<int GATHER>
__global__ __launch_bounds__(256) void mfma_g3_kernel(
    const float* __restrict__ A, const int* __restrict__ gidx,
    int lda, int K,
    const float* __restrict__ W, int ldw,
    const float* __restrict__ bias1, const float* __restrict__ bias2,
    float* __restrict__ out)
{
    const int wv   = threadIdx.x >> 6;
    const int lane = threadIdx.x & 63;
    const int row  = lane & 15;
    const int quad = lane >> 4;
    const int m0   = blockIdx.x * 64 + wv * 16;
    const int gate = blockIdx.y >> 3;
    const int gbase = (gate == 0) ? 0 : (gate == 1 ? 1024 : 1536);
    const int j0   = (blockIdx.y & 7) * 64;

    const int arow = GATHER ? gidx[m0 + row] : (m0 + row);

    ffrag acc[4];
#pragma unroll
    for (int n = 0; n < 4; ++n)
#pragma unroll
        for (int r = 0; r < 4; ++r) acc[n][r] = 0.0f;

    for (int k0 = 0; k0 < K; k0 += 32) {
        const bool tail = (k0 + 32 > K);
        float av[8];
        if (!tail) {
            const float* ap = A + (size_t)arow * lda + k0 + quad * 8;
            float4 aA = *(const float4*)ap;
            float4 aB = *(const float4*)(ap + 4);
            av[0]=aA.x; av[1]=aA.y; av[2]=aA.z; av[3]=aA.w;
            av[4]=aB.x; av[5]=aB.y; av[6]=aB.z; av[7]=aB.w;
        } else {
#pragma unroll
            for (int z = 0; z < 8; ++z) {
                int kk = k0 + quad * 8 + z;
                av[z] = (kk < K) ? A[(size_t)arow * lda + kk] : 0.0f;
            }
        }
        bfrag ahi, alo;
        cvt_hilo(av, ahi, alo);
#pragma unroll
        for (int n = 0; n < 4; ++n) {
            const int wrow = gbase + j0 + n * 16 + row;
            float wvv[8];
            if (!tail) {
                const float* wp = W + (size_t)wrow * ldw + k0 + quad * 8;
                float4 wA = *(const float4*)wp;
                float4 wB = *(const float4*)(wp + 4);
                wvv[0]=wA.x; wvv[1]=wA.y; wvv[2]=wA.z; wvv[3]=wA.w;
                wvv[4]=wB.x; wvv[5]=wB.y; wvv[6]=wB.z; wvv[7]=wB.w;
            } else {
#pragma unroll
                for (int z = 0; z < 8; ++z) {
                    int kk = k0 + quad * 8 + z;
                    wvv[z] = (kk < K) ? W[(size_t)wrow * ldw + kk] : 0.0f;
                }
            }
            bfrag whi, wlo;
            cvt_hilo(wvv, whi, wlo);
            acc[n] = __builtin_amdgcn_mfma_f32_16x16x32_bf16(ahi, whi, acc[n], 0, 0, 0);
            acc[n] = __builtin_amdgcn_mfma_f32_16x16x32_bf16(alo, whi, acc[n], 0, 0, 0);
            acc[n] = __builtin_amdgcn_mfma_f32_16x16x32_bf16(ahi, wlo, acc[n], 0, 0, 0);
        }
    }
#pragma unroll
    for (int n = 0; n < 4; ++n) {
        const int j = j0 + n * 16 + row;
        const float bb = bias1[gbase + j] + bias2[gbase + j];
#pragma unroll
        for (int r = 0; r < 4; ++r) {
            const int m = m0 + quad * 4 + r;
            out[((size_t)m * 3 + gate) * 512 + j] = acc[n][r] + bb;
        }
    }
}

// ---------------------------------------------------------------------------
// G3 GEMM (validated R21): G3[t,b,:] = W3 . h_s[t,b,:], bf16 pair-packed.
// ---------------------------------------------------------------------------
__global__ __launch_bounds__(256) void g3pack_kernel(
    const float* __restrict__ A,            // Rh: 4096 x 512
    const float* __restrict__ W,            // Wih_m, ldw 1024
    unsigned short* __restrict__ G3s,
    int mbase)                              // 0 or 4096
{
    const int wv   = threadIdx.x >> 6;
    const int lane = threadIdx.x & 63;
    const int row  = lane & 15;
    const int quad = lane >> 4;
    const int m0   = blockIdx.x * 64 + wv * 16;
    const int gate = blockIdx.y >> 3;
    const int gbase = (gate == 0) ? 0 : (gate == 1 ? 1024 : 1536);
    const int j0   = (blockIdx.y & 7) * 64;

    ffrag acc[4];
#pragma unroll
    for (int n = 0; n < 4; ++n)
#pragma unroll
        for (int r = 0; r < 4; ++r) acc[n][r] = 0.0f;

    for (int k0 = 0; k0 < 512; k0 += 32) {
        const float* ap = A + (size_t)(m0 + row) * 512 + k0 + quad * 8;
        float4 aA = *(const float4*)ap;
        float4 aB = *(const float4*)(ap + 4);
        float av[8] = {aA.x, aA.y, aA.z, aA.w, aB.x, aB.y, aB.z, aB.w};
        bfrag ahi, alo;
        cvt_hilo(av, ahi, alo);
#pragma unroll
        for (int n = 0; n < 4; ++n) {
            const int wrow = gbase + j0 + n * 16 + row;
            const float* wp = W + (size_t)wrow * 1024 + k0 + quad * 8;
            float4 wA = *(const float4*)wp;
            float4 wB = *(const float4*)(wp + 4);
            float wvv[8] = {wA.x, wA.y, wA.z, wA.w, wB.x, wB.y, wB.z, wB.w};
            bfrag whi, wlo;
            cvt_hilo(wvv, whi, wlo);
            acc[n] = __builtin_amdgcn_mfma_f32_16x16x32_bf16(ahi, whi, acc[n], 0, 0, 0);
            acc[n] = __builtin_amdgcn_mfma_f32_16x16x32_bf16(alo, whi, acc[n], 0, 0, 0);
            acc[n] = __builtin_amdgcn_mfma_f32_16x16x32_bf16(ahi, wlo, acc[n], 0, 0, 0);
        }
    }
#pragma unroll
    for (int n = 0; n < 4; ++n) {
        const int j = j0 + n * 16 + row;
#pragma unroll
        for (int r = 0; r < 4; ++r) {
            const int mg = mbase + m0 + quad * 4 + r;
            const int t = mg >> 7, b = mg & 127;
            size_t idx = (((size_t)(t >> 1) * 128 + b) * 1536 + gate * 512 + j) * 2
                       + (t & 1);
            G3s[idx] = (unsigned short)f2bf(acc[n][r]);
        }
    }
}

// ---------------------------------------------------------------------------
// Encoder gate math (validated R15).
// ---------------------------------------------------------------------------
__global__ __launch_bounds__(256) void enc_gates_kernel(
    const float* __restrict__ P, float* __restrict__ h)
{
    const int i = blockIdx.x * 256 + threadIdx.x;
    const int m = i >> 7;
    const int j4 = (i & 127) * 4;
    const float* p = P + (size_t)m * 1536 + j4;
    float4 gi = *(const float4*)p;
    float4 gg = *(const float4*)(p + 512);
    float4 go = *(const float4*)(p + 1024);
    float4 r;
    r.x = fast_sigmoid(go.x) * fast_tanh(fast_sigmoid(gi.x) * fast_tanh(gg.x));
    r.y = fast_sigmoid(go.y) * fast_tanh(fast_sigmoid(gi.y) * fast_tanh(gg.y));
    r.z = fast_sigmoid(go.z) * fast_tanh(fast_sigmoid(gi.z) * fast_tanh(gg.z));
    r.w = fast_sigmoid(go.w) * fast_tanh(fast_sigmoid(gi.w) * fast_tanh(gg.w));
    *(float4*)&h[(size_t)m * 512 + j4] = r;
}

// ---------------------------------------------------------------------------
// Wm pack (validated R19): [kc][nt][lane] tile-interleaved.
// ---------------------------------------------------------------------------
__global__ __launch_bounds__(256) void pack_wm_kernel(
    const float* __restrict__ Wm, unsigned* __restrict__ WmB)
{
    int i = blockIdx.x * 256 + threadIdx.x;           // 0 .. 131071
    int u = i & 3, lane = (i >> 2) & 63;
    int nt = (i >> 8) & 31, kc = i >> 13;
    int row = nt * 16 + (lane & 15);
    int k = kc * 32 + ((lane >> 4) << 3) + u * 2;
    unsigned lo = f2bf(Wm[(size_t)row * 512 + k]);
    unsigned hi = f2bf(Wm[(size_t)row * 512 + k + 1]);
    WmB[i] = lo | (hi << 16);
}

// ---------------------------------------------------------------------------
// Phase B (Round 22): pre_s LDS-cached; GEMV1 K-split; G3-sum unroll 4.
// ---------------------------------------------------------------------------
__global__ __launch_bounds__(1024) void phaseB_kernel(
    const float* __restrict__ pre_s, const float* __restrict__ pre_t,
    const float* __restrict__ pre_m_h,
    const unsigned* __restrict__ WmB, const unsigned* __restrict__ G3u,
    const float* __restrict__ w_e,
    const float* __restrict__ fc_w,  const float* __restrict__ fc_b,
    float* __restrict__ out)
{
    extern __shared__ __align__(16) float psL[];      // 64*512 fp32 = 128KB
    __shared__ __align__(16) float hm[512];
    __shared__ __align__(16) float base[512];
    __shared__ __align__(16) float wesh[512];
    __shared__ __align__(16) float sc[64];
    __shared__ __align__(16) float red3[3 * 2 * 512];
    __shared__ __align__(16) unsigned short hmh[512];
    __shared__ __align__(16) unsigned short hml[512];

    const int b    = blockIdx.x;
    const int tid  = threadIdx.x;
    const int wv   = tid >> 6;
    const int lane = tid & 63;
    const int j    = tid & 511;
    const int kh   = tid >> 9;
    const int quad = lane >> 4;

    if (tid < 512) {
        wesh[tid] = w_e[tid];
        hm[tid] = 0.0f; hmh[tid] = 0; hml[tid] = 0;
    }
    // pre_s[t,b,:] -> LDS once (exact fp32), reused all 64 steps
    for (int i = tid; i < 32768; i += 1024) {
        int t = i >> 9, h = i & 511;
        psL[i] = ntload(&pre_s[((size_t)t * 128 + b) * 512 + h]);
    }
    __syncthreads();

    for (int k = 0; k < 64; ++k) {
        // ---- GEMV1 (K-split): partials for base = Wm . hm
        {
            const int kh2 = wv >> 3;               // K-half 0/1
            const int tp  = (wv & 7) * 4;          // 4 tiles per wave
            ffrag a0 = {0.0f,0.0f,0.0f,0.0f}, a1 = {0.0f,0.0f,0.0f,0.0f};
            ffrag a2 = {0.0f,0.0f,0.0f,0.0f}, a3 = {0.0f,0.0f,0.0f,0.0f};
            const uint4* wp = (const uint4*)WmB
                            + ((size_t)(kh2 * 8) * 32 + tp) * 64 + lane;
            const unsigned short* ab = ((lane & 8) == 0) ? hmh : hml;
#pragma unroll 1
            for (int kc = 0; kc < 8; ++kc) {
                bfrag a  = *(const bfrag*)&ab[(kh2 * 8 + kc) * 32 + quad * 8];
                bfrag w0 = *(const bfrag*)(wp);
                bfrag w1 = *(const bfrag*)(wp + 64);
                bfrag w2 = *(const bfrag*)(wp + 128);
                bfrag w3 = *(const bfrag*)(wp + 192);
                a0 = __builtin_amdgcn_mfma_f32_16x16x32_bf16(a, w0, a0, 0, 0, 0);
                a1 = __builtin_amdgcn_mfma_f32_16x16x32_bf16(a, w1, a1, 0, 0, 0);
                a2 = __builtin_amdgcn_mfma_f32_16x16x32_bf16(a, w2, a2, 0, 0, 0);
                a3 = __builtin_amdgcn_mfma_f32_16x16x32_bf16(a, w3, a3, 0, 0, 0);
                wp += 2048;                        // next kc (32 tiles * 64)
            }
            float s0 = a0[0] + __shfl_xor(a0[0], 32);
            float s1 = a1[0] + __shfl_xor(a1[0], 32);
            float s2 = a2[0] + __shfl_xor(a2[0], 32);
            float s3 = a3[0] + __shfl_xor(a3[0], 32);
            if (lane < 16) {
                float* rr = &red3[kh2 * 512];
                rr[(tp + 0) * 16 + lane] = s0;
                rr[(tp + 1) * 16 + lane] = s1;
                rr[(tp + 2) * 16 + lane] = s2;
                rr[(tp + 3) * 16 + lane] = s3;
            }
        }
        __syncthreads();
        if (tid < 512)
            base[tid] = red3[tid] + red3[512 + tid]
                      + ntload(&pre_t[((size_t)k * 128 + b) * 512 + tid]);
        __syncthreads();

        // ---- attention scores: e[t] = w_e . tanh(psL[t] + base)  (all LDS)
#pragma unroll
        for (int tt = 0; tt < 4; ++tt) {
            int t = wv * 4 + tt;
            const float* ps = &psL[t * 512];
            float p = 0.0f;
#pragma unroll
            for (int u = 0; u < 8; ++u) {
                int h = lane + 64 * u;
                p += wesh[h] * fast_tanh(ps[h] + base[h]);
            }
#pragma unroll
            for (int off = 32; off; off >>= 1) p += __shfl_xor(p, off);
            if (lane == 0) sc[t] = p;
        }
        __syncthreads();

        // ---- softmax over 64 premise positions
        if (wv == 0) {
            float s = sc[lane], mx = s;
#pragma unroll
            for (int off = 32; off; off >>= 1) mx = fmaxf(mx, __shfl_xor(mx, off));
            float e = __expf(s - mx), sum = e;
#pragma unroll
            for (int off = 32; off; off >>= 1) sum += __shfl_xor(sum, off);
            sc[lane] = e / sum;
        }
        __syncthreads();

        // ---- gates partials = sum_t alpha_t * G3[t,b,:]  (L2-resident now)
        {
            const unsigned* gb = G3u + ((size_t)(kh * 16) * 128 + b) * 1536 + j;
            float p0 = 0.0f, p1 = 0.0f, p2 = 0.0f;
#pragma unroll 4
            for (int tpi = 0; tpi < 16; ++tpi) {
                const unsigned* gt = gb + (size_t)tpi * 196608;   // 128*1536
                unsigned u0 = gt[0];
                unsigned u1 = gt[512];
                unsigned u2 = gt[1024];
                float2 al = *(const float2*)&sc[(kh * 16 + tpi) * 2];
                p0 += blo(u0) * al.x + bhi(u0) * al.y;
                p1 += blo(u1) * al.x + bhi(u1) * al.y;
                p2 += blo(u2) * al.x + bhi(u2) * al.y;
            }
            red3[kh * 512 + j]       = p0;
            red3[(2 + kh) * 512 + j] = p1;
            red3[(4 + kh) * 512 + j] = p2;
        }
        __syncthreads();

        // ---- gate math -> hm (+ hi/lo pack for next step's GEMV1)
        if (tid < 512) {
            const size_t m = (size_t)k * 128 + b;
            float gi = red3[tid]        + red3[512 + tid]
                     + ntload(&pre_m_h[(m * 3 + 0) * 512 + tid]);
            float gg = red3[1024 + tid] + red3[1536 + tid]
                     + ntload(&pre_m_h[(m * 3 + 1) * 512 + tid]);
            float go = red3[2048 + tid] + red3[2560 + tid]
                     + ntload(&pre_m_h[(m * 3 + 2) * 512 + tid]);
            float cc = fast_sigmoid(gi) * fast_tanh(gg);
            float hv = fast_sigmoid(go) * fast_tanh(cc);
            hm[tid] = hv;
            unsigned hb = f2bf(hv);
            hmh[tid] = (unsigned short)hb;
            hml[tid] = (unsigned short)f2bf(hv - blo(hb));
        }
        __syncthreads();
    }

    if (wv < 3) {
        float p = 0.0f;
#pragma unroll
        for (int u = 0; u < 8; ++u) {
            int h = lane + 64 * u;
            p += hm[h] * fc_w[wv * 512 + h];
        }
#pragma unroll
        for (int off = 32; off; off >>= 1) p += __shfl_xor(p, off);
        if (lane == 0) out[b * 3 + wv] = p + fc_b[wv];
    }
}

extern "C" void kernel_launch(void* const* d_in, const int* in_sizes, int n_in,
                              void* d_out, int out_size, void* d_ws, size_t ws_size,
                              hipStream_t stream)
{
    (void)in_sizes; (void)n_in; (void)out_size;
    const int*   premise    = (const int*)d_in[0];
    const int*   hypothesis = (const int*)d_in[2];
    const float* embed  = (const float*)d_in[4];
    const float* w_e    = (const float*)d_in[5];
    const float* Ws     = (const float*)d_in[6];
    const float* Wt     = (const float*)d_in[7];
    const float* Wm     = (const float*)d_in[8];
    const float* Wih_p  = (const float*)d_in[9];
    const float* bih_p  = (const float*)d_in[10];
    const float* bhh_p  = (const float*)d_in[11];
    const float* Wih_h  = (const float*)d_in[12];
    const float* bih_h  = (const float*)d_in[13];
    const float* bhh_h  = (const float*)d_in[14];
    const float* Wih_m  = (const float*)d_in[15];
    const float* bih_m  = (const float*)d_in[16];
    const float* bhh_m  = (const float*)d_in[17];
    const float* fc_w   = (const float*)d_in[18];
    const float* fc_b   = (const float*)d_in[19];

    // Workspace layout (floats), total 29,360,128 <= guard:
    //   Rh      @ 0         : 2,097,152  (half-scratch; WmB aliases)
    //   pre_s   @ 2,097,152 : 4,194,304
    //   pre_t   @ 6,291,456 : 4,194,304
    //   pre_m_h @10,485,760 :12,582,912  (halves also = encoder preact P)
    //   G3      @23,068,672 : 6,291,456  (bf16 pairs as uints)
    float* ws      = (float*)d_ws;
    float* Rh      = ws;
    float* pre_s   = ws + 2097152;
    float* pre_t   = ws + 6291456;
    float* pre_m_h = ws + 10485760;
    unsigned* G3u  = (unsigned*)(ws + 23068672);
    unsigned short* G3s = (unsigned short*)G3u;
    unsigned* WmB  = (unsigned*)Rh;           // aliases Rh after last reader
    float* outp    = (float*)d_out;
    if (ws_size < (size_t)29556736 * 4) return;

    dim3 blk(256);

    // ---- Phase A: premise halves -> h_s(half) -> pre_s(half), G3(half)
    for (int h = 0; h < 2; ++h) {
        float* P = pre_m_h + (size_t)h * 6291456;
        mfma_g3_kernel<1><<<dim3(64, 24), blk, 0, stream>>>(
            embed, premise + h * 4096, 300, 300, Wih_p, 300, bih_p, bhh_p, P);
        enc_gates_kernel<<<2048, blk, 0, stream>>>(P, Rh);
        mfma_nt_kernel<<<dim3(64, 8), blk, 0, stream>>>(
            Rh, Ws, pre_s + (size_t)h * 2097152);
        g3pack_kernel<<<dim3(64, 24), blk, 0, stream>>>(
            Rh, Wih_m, G3s, h * 4096);
    }
    // ---- Phase A: hypothesis halves -> h_t(half) -> pre_t(half), pre_m_h(half)
    for (int h = 0; h < 2; ++h) {
        float* P = pre_m_h + (size_t)h * 6291456;
        mfma_g3_kernel<1><<<dim3(64, 24), blk, 0, stream>>>(
            embed, hypothesis + h * 4096, 300, 300, Wih_h, 300, bih_h, bhh_h, P);
        enc_gates_kernel<<<2048, blk, 0, stream>>>(P, Rh);
        mfma_nt_kernel<<<dim3(64, 8), blk, 0, stream>>>(
            Rh, Wt, pre_t + (size_t)h * 2097152);
        mfma_g3_kernel<0><<<dim3(64, 24), blk, 0, stream>>>(
            Rh, nullptr, 512, 512, Wih_m + 512, 1024, bih_m, bhh_m,
            pre_m_h + (size_t)h * 6291456);
    }

    // ---- Wm pack (after Rh's last reader; output aliases Rh)
    pack_wm_kernel<<<512, blk, 0, stream>>>(Wm, WmB);

    // ---- Phase B (128KB dynamic LDS for pre_s cache)
    static int attr_done = 0;
    if (!attr_done) {
        hipFuncSetAttribute((const void*)phaseB_kernel,
                            hipFuncAttributeMaxDynamicSharedMemorySize, 131072);
        attr_done = 1;
    }
    phaseB_kernel<<<dim3(128), dim3(1024), 131072, stream>>>(
        pre_s, pre_t, pre_m_h, WmB, G3u, w_e, fc_w, fc_b, outp);
}